// Round 9
// baseline (137.157 us; speedup 1.0000x reference)
//
#include <hip/hip_runtime.h>

#define NN 40000
#define NE 640000
#define D 128
#define CAP 64  // bucket capacity; P(Poisson(16) >= 64) ~ 3e-22

typedef __attribute__((ext_vector_type(8))) short short8;
typedef __attribute__((ext_vector_type(4))) float f32x4;
typedef __attribute__((ext_vector_type(4))) int i32x4;

__device__ __forceinline__ short f2b(float v) {
  unsigned int u = __builtin_bit_cast(unsigned int, v);
  u = (u + 0x7fffu + ((u >> 16) & 1u)) >> 16;
  return (short)u;
}
__device__ __forceinline__ float b2f(short s) {
  unsigned int u = ((unsigned int)(unsigned short)s) << 16;
  return __builtin_bit_cast(float, u);
}

// ---------------- K0: weights (bf16 transpose + Wg hi/lo split), zero cnt,
// zero dummy h-row (index NN) used for branchless gather padding -----------
__global__ __launch_bounds__(256) void k_prep(
    const float* __restrict__ Wn, const float* __restrict__ Wg,
    const float* __restrict__ Wa, short* __restrict__ WnT,
    short* __restrict__ WgThi, short* __restrict__ WgTlo,
    short* __restrict__ WaT, int* __restrict__ cnt, short* __restrict__ h) {
  int i = blockIdx.x * 256 + threadIdx.x;  // 0..16383
  int k = i >> 7, c = i & 127;
  WnT[c * D + k] = f2b(Wn[k * D + c]);
  WaT[c * D + k] = f2b(Wa[k * D + c]);
  float v = Wg[k * D + c];
  short hi = f2b(v);
  WgThi[c * D + k] = hi;
  WgTlo[c * D + k] = f2b(v - b2f(hi));
  if (i < 10000) {  // zero cnt: 40000 ints = 10000 int4
    i32x4 z = {0, 0, 0, 0};
    *(i32x4*)(cnt + i * 4) = z;
  }
  if (i < 16) {  // zero dummy row h[NN]
    short8 z = {0, 0, 0, 0, 0, 0, 0, 0};
    *(short8*)(h + (size_t)NN * D + i * 8) = z;
  }
}

// ---------------- K1: node transform + edge fill (block-split) ------------
// Blocks [0,2500): 16 rows node transform. Blocks [2500,5000): 256 edges.
// A-frag: lane l holds row (l&15), k = kt*32 + (l>>4)*8 + j
// B-frag: lane l holds col (l&15), same k slots -> permutation-safe.
// C/D: col = lane&15, row = (lane>>4)*4 + reg
__global__ __launch_bounds__(256) void k_nf(
    const float* __restrict__ x, const short* __restrict__ WaT,
    const float* __restrict__ ba, short* __restrict__ h_out,
    short* __restrict__ xbf_out, const int* __restrict__ ei,
    int* __restrict__ cnt, unsigned short* __restrict__ bucket) {
  int bid = blockIdx.x;
  if (bid >= 2500) {
    int e = (bid - 2500) * 256 + threadIdx.x;  // 2500*256 == NE exactly
    int r = ei[e];       // destination row
    int c = ei[NE + e];  // source col
    int slot = atomicAdd(&cnt[r], 1);
    if (slot < CAP) bucket[(size_t)r * CAP + slot] = (unsigned short)c;
    return;
  }
  __shared__ float al_s[16][132];
  int r0 = bid * 16;
  int w = threadIdx.x >> 6, l = threadIdx.x & 63;
  int g = l >> 4, c16 = l & 15;
  int rowA = r0 + c16;

  f32x4 xf[8];
  short8 a[4];
#pragma unroll
  for (int kt = 0; kt < 4; ++kt) {
    const float* p = x + (size_t)rowA * D + kt * 32 + g * 8;
    f32x4 v0 = *(const f32x4*)p;
    f32x4 v1 = *(const f32x4*)(p + 4);
    xf[kt * 2] = v0;
    xf[kt * 2 + 1] = v1;
    short8 t;
    t[0] = f2b(v0[0]); t[1] = f2b(v0[1]); t[2] = f2b(v0[2]); t[3] = f2b(v0[3]);
    t[4] = f2b(v1[0]); t[5] = f2b(v1[1]); t[6] = f2b(v1[2]); t[7] = f2b(v1[3]);
    a[kt] = t;
    *(short8*)(xbf_out + (size_t)rowA * D + kt * 32 + g * 8) = t;
  }

#pragma unroll
  for (int u = 0; u < 2; ++u) {
    int ct = w * 2 + u;
    int cc = ct * 16 + c16;
    f32x4 c = {0.f, 0.f, 0.f, 0.f};
#pragma unroll
    for (int kt = 0; kt < 4; ++kt) {
      short8 b = *(const short8*)(WaT + (size_t)cc * D + kt * 32 + g * 8);
      c = __builtin_amdgcn_mfma_f32_16x16x32_bf16(a[kt], b, c, 0, 0, 0);
    }
    float bav = ba[cc];
#pragma unroll
    for (int r = 0; r < 4; ++r) {
      float t = c[r] + bav;
      al_s[g * 4 + r][cc] = 1.0f / (1.0f + __expf(-t));
    }
  }
  __syncthreads();

  short8 hh;
#pragma unroll
  for (int q = 0; q < 8; ++q) {
    float av = al_s[c16][w * 32 + g * 8 + q];
    float xv = xf[w * 2 + (q >> 2)][q & 3];
    hh[q] = f2b(xv * av);
  }
  *(short8*)(h_out + (size_t)rowA * D + w * 32 + g * 8) = hh;
}

// one pair-step: slots 4*T0+g and 4*T0+4+g for both nodes; 4 independent
// 16B gathers, register indices, branchless dummy-row clamp.
#define PSTEP(T0, C0A, C0B, C1A, C1B)                               \
  {                                                                 \
    int s0 = 4 * (T0) + g, s1 = s0 + 4;                             \
    int ra0 = s0 < deg0 ? (C0A) : NN;                               \
    int ra1 = s1 < deg0 ? (C0B) : NN;                               \
    int rb0 = s0 < deg1 ? (C1A) : NN;                               \
    int rb1 = s1 < deg1 ? (C1B) : NN;                               \
    short8 va0 = *(const short8*)(h + (size_t)ra0 * D + i * 8);     \
    short8 va1 = *(const short8*)(h + (size_t)ra1 * D + i * 8);     \
    short8 vb0 = *(const short8*)(h + (size_t)rb0 * D + i * 8);     \
    short8 vb1 = *(const short8*)(h + (size_t)rb1 * D + i * 8);     \
    _Pragma("unroll") for (int q = 0; q < 8; ++q) {                 \
      a0[q] += b2f(va0[q]) + b2f(va1[q]);                           \
      a1[q] += b2f(vb0[q]) + b2f(vb1[q]);                           \
    }                                                               \
  }

// ---------------- K2: fused aggregate + output GEMM (512 thr, 8 waves) ----
// Block = 16 nodes. Phase A: wave w -> node pair (base+2w, +1); indices
// hoisted to registers via shfl batches; unrolled wave-uniform bodies.
// Phase B: wave w computes output cols [16w, 16w+16).
__global__ __launch_bounds__(512) void k_fused(
    const int* __restrict__ cnt, const unsigned short* __restrict__ bucket,
    const short* __restrict__ h, const short* __restrict__ xbf,
    const short* __restrict__ WnT, const short* __restrict__ WgThi,
    const short* __restrict__ WgTlo, const float* __restrict__ bn,
    const float* __restrict__ bg, float* __restrict__ out) {
  __shared__ float st[16][132];
  int w = threadIdx.x >> 6, l = threadIdx.x & 63;
  int g = l >> 4, i = l & 15;
  int base = blockIdx.x * 16;

  // ---- Phase A ----
  {
    int n0 = base + 2 * w, n1 = n0 + 1;
    int deg0 = cnt[n0]; deg0 = deg0 < CAP ? deg0 : CAP;
    int deg1 = cnt[n1]; deg1 = deg1 < CAP ? deg1 : CAP;
    int dmax = deg0 > deg1 ? deg0 : deg1;
    int bc0 = bucket[(size_t)n0 * CAP + l];
    int bc1 = bucket[(size_t)n1 * CAP + l];
    float a0[8], a1[8];
#pragma unroll
    for (int q = 0; q < 8; ++q) { a0[q] = 0.f; a1[q] = 0.f; }

    // slots < 16: shfls hoisted (typical path, deg<=16 is ~55% of nodes)
    int c00 = __shfl(bc0, g), c01 = __shfl(bc0, 4 + g);
    int c02 = __shfl(bc0, 8 + g), c03 = __shfl(bc0, 12 + g);
    int c10 = __shfl(bc1, g), c11 = __shfl(bc1, 4 + g);
    int c12 = __shfl(bc1, 8 + g), c13 = __shfl(bc1, 12 + g);
    PSTEP(0, c00, c01, c10, c11);
    if (dmax > 8) PSTEP(2, c02, c03, c12, c13);
    if (dmax > 16) {
      int c04 = __shfl(bc0, 16 + g), c05 = __shfl(bc0, 20 + g);
      int c14 = __shfl(bc1, 16 + g), c15 = __shfl(bc1, 20 + g);
      PSTEP(4, c04, c05, c14, c15);
    }
    if (dmax > 24) {
      int c06 = __shfl(bc0, 24 + g), c07 = __shfl(bc0, 28 + g);
      int c16_ = __shfl(bc1, 24 + g), c17 = __shfl(bc1, 28 + g);
      PSTEP(6, c06, c07, c16_, c17);
    }
    if (dmax > 32) {  // rare: P(deg>32 | Poisson(16)) ~ 1e-4
      for (int j = 32; j < dmax; j += 8) {
        int s0 = j + g, s1 = j + 4 + g;
        int d00 = __shfl(bc0, s0 & 63), d01 = __shfl(bc0, s1 & 63);
        int d10 = __shfl(bc1, s0 & 63), d11 = __shfl(bc1, s1 & 63);
        int ra0 = s0 < deg0 ? d00 : NN;
        int ra1 = s1 < deg0 ? d01 : NN;
        int rb0 = s0 < deg1 ? d10 : NN;
        int rb1 = s1 < deg1 ? d11 : NN;
        short8 va0 = *(const short8*)(h + (size_t)ra0 * D + i * 8);
        short8 va1 = *(const short8*)(h + (size_t)ra1 * D + i * 8);
        short8 vb0 = *(const short8*)(h + (size_t)rb0 * D + i * 8);
        short8 vb1 = *(const short8*)(h + (size_t)rb1 * D + i * 8);
#pragma unroll
        for (int q = 0; q < 8; ++q) {
          a0[q] += b2f(va0[q]) + b2f(va1[q]);
          a1[q] += b2f(vb0[q]) + b2f(vb1[q]);
        }
      }
    }
#pragma unroll
    for (int q = 0; q < 8; ++q) {
      a0[q] += __shfl_xor(a0[q], 16);
      a0[q] += __shfl_xor(a0[q], 32);
      a1[q] += __shfl_xor(a1[q], 16);
      a1[q] += __shfl_xor(a1[q], 32);
    }
    if (g == 0) {
      f32x4 lo = {a0[0], a0[1], a0[2], a0[3]};
      f32x4 hi = {a0[4], a0[5], a0[6], a0[7]};
      *(f32x4*)&st[w * 2][i * 8] = lo;
      *(f32x4*)&st[w * 2][i * 8 + 4] = hi;
    } else if (g == 1) {
      f32x4 lo = {a1[0], a1[1], a1[2], a1[3]};
      f32x4 hi = {a1[4], a1[5], a1[6], a1[7]};
      *(f32x4*)&st[w * 2 + 1][i * 8] = lo;
      *(f32x4*)&st[w * 2 + 1][i * 8 + 4] = hi;
    }
  }
  __syncthreads();

  // ---- Phase B: wave w computes cols [w*16, w*16+16) ----
  int rowG = base + i;
  int cc = w * 16 + i;
  f32x4 c = {0.f, 0.f, 0.f, 0.f};
  float bias = bn[cc] + bg[cc];
#pragma unroll
  for (int kt = 0; kt < 4; ++kt) {
    short8 axf = *(const short8*)(xbf + (size_t)rowG * D + kt * 32 + g * 8);
    const float* p = &st[i][kt * 32 + g * 8];
    f32x4 v0 = *(const f32x4*)p;
    f32x4 v1 = *(const f32x4*)(p + 4);
    short8 sh, sl;
#pragma unroll
    for (int jq = 0; jq < 4; ++jq) {
      short hh = f2b(v0[jq]);
      sh[jq] = hh;
      sl[jq] = f2b(v0[jq] - b2f(hh));
    }
#pragma unroll
    for (int jq = 0; jq < 4; ++jq) {
      short hh = f2b(v1[jq]);
      sh[4 + jq] = hh;
      sl[4 + jq] = f2b(v1[jq] - b2f(hh));
    }
    short8 bwn = *(const short8*)(WnT + (size_t)cc * D + kt * 32 + g * 8);
    short8 bh = *(const short8*)(WgThi + (size_t)cc * D + kt * 32 + g * 8);
    short8 bl = *(const short8*)(WgTlo + (size_t)cc * D + kt * 32 + g * 8);
    c = __builtin_amdgcn_mfma_f32_16x16x32_bf16(axf, bwn, c, 0, 0, 0);
    c = __builtin_amdgcn_mfma_f32_16x16x32_bf16(sh, bh, c, 0, 0, 0);
    c = __builtin_amdgcn_mfma_f32_16x16x32_bf16(sl, bh, c, 0, 0, 0);
    c = __builtin_amdgcn_mfma_f32_16x16x32_bf16(sh, bl, c, 0, 0, 0);
  }
#pragma unroll
  for (int r = 0; r < 4; ++r) {
    int rr = base + g * 4 + r;
    out[(size_t)rr * D + cc] = tanhf(c[r] + bias);
  }
}

extern "C" void kernel_launch(void* const* d_in, const int* in_sizes, int n_in,
                              void* d_out, int out_size, void* d_ws,
                              size_t ws_size, hipStream_t stream) {
  const float* x = (const float*)d_in[0];
  const int* ei = (const int*)d_in[1];
  const float* Wn_w = (const float*)d_in[2];
  const float* Wn_b = (const float*)d_in[3];
  const float* Wg_w = (const float*)d_in[4];
  const float* Wg_b = (const float*)d_in[5];
  const float* Wa_w = (const float*)d_in[6];
  const float* Wa_b = (const float*)d_in[7];

  char* ws = (char*)d_ws;
  short* WaT = (short*)(ws + 0);
  short* WnT = (short*)(ws + 32 * 1024);
  short* WgThi = (short*)(ws + 64 * 1024);
  short* WgTlo = (short*)(ws + 96 * 1024);
  int* cnt = (int*)(ws + 128 * 1024);  // 160 KB
  size_t off = 512 * 1024;
  short* h = (short*)(ws + off);  // (NN+1)*D*2 = 10.24 MB (+dummy row)
  off += (size_t)(NN + 1) * D * 2;
  short* xbf = (short*)(ws + off);  // 10.24 MB
  off += (size_t)NN * D * 2;
  unsigned short* bucket = (unsigned short*)(ws + off);  // 5.12 MB
  float* out = (float*)d_out;

  k_prep<<<64, 256, 0, stream>>>(Wn_w, Wg_w, Wa_w, WnT, WgThi, WgTlo, WaT,
                                 cnt, h);
  k_nf<<<5000, 256, 0, stream>>>(x, WaT, Wa_b, h, xbf, ei, cnt, bucket);
  k_fused<<<2500, 512, 0, stream>>>(cnt, bucket, h, xbf, WnT, WgThi, WgTlo,
                                    Wn_b, Wg_b, out);
}

// Round 10
// 106.958 us; speedup vs baseline: 1.2823x; 1.2823x over previous
//
#include <hip/hip_runtime.h>

#define NN 40000
#define NE 640000
#define D 128
#define CAP 64  // bucket capacity; P(Poisson(16) >= 64) ~ 3e-22

typedef __attribute__((ext_vector_type(8))) short short8;
typedef __attribute__((ext_vector_type(4))) float f32x4;
typedef __attribute__((ext_vector_type(4))) int i32x4;

__device__ __forceinline__ short f2b(float v) {
  unsigned int u = __builtin_bit_cast(unsigned int, v);
  u = (u + 0x7fffu + ((u >> 16) & 1u)) >> 16;
  return (short)u;
}
__device__ __forceinline__ float b2f(short s) {
  unsigned int u = ((unsigned int)(unsigned short)s) << 16;
  return __builtin_bit_cast(float, u);
}

// ---------------- K0: weights (bf16 transpose + Wg hi/lo split), zero cnt,
// zero dummy h-row (index NN) used for branchless gather padding -----------
__global__ __launch_bounds__(256) void k_prep(
    const float* __restrict__ Wn, const float* __restrict__ Wg,
    const float* __restrict__ Wa, short* __restrict__ WnT,
    short* __restrict__ WgThi, short* __restrict__ WgTlo,
    short* __restrict__ WaT, int* __restrict__ cnt, short* __restrict__ h) {
  int i = blockIdx.x * 256 + threadIdx.x;  // 0..16383
  int k = i >> 7, c = i & 127;
  WnT[c * D + k] = f2b(Wn[k * D + c]);
  WaT[c * D + k] = f2b(Wa[k * D + c]);
  float v = Wg[k * D + c];
  short hi = f2b(v);
  WgThi[c * D + k] = hi;
  WgTlo[c * D + k] = f2b(v - b2f(hi));
  if (i < 10000) {  // zero cnt: 40000 ints = 10000 int4
    i32x4 z = {0, 0, 0, 0};
    *(i32x4*)(cnt + i * 4) = z;
  }
  if (i < 16) {  // zero dummy row h[NN]
    short8 z = {0, 0, 0, 0, 0, 0, 0, 0};
    *(short8*)(h + (size_t)NN * D + i * 8) = z;
  }
}

// ---------------- K1: edge bucket fill (u16 cols) ----------------
__global__ __launch_bounds__(256) void k_fill(
    const int* __restrict__ ei, int* __restrict__ cnt,
    unsigned short* __restrict__ bucket) {
  int e = blockIdx.x * 256 + threadIdx.x;
  if (e >= NE) return;
  int r = ei[e];       // destination row
  int c = ei[NE + e];  // source col
  int slot = atomicAdd(&cnt[r], 1);
  if (slot < CAP) bucket[(size_t)r * CAP + slot] = (unsigned short)c;
}

// ---------------- K2: node transform (16 rows/block, LDS-staged x) --------
// x tile loaded COALESCED into LDS, frags built from LDS.
// A-frag: lane l holds row (l&15), k = kt*32 + (l>>4)*8 + j
// B-frag: lane l holds col (l&15), same k slots -> permutation-safe.
// C/D: col = lane&15, row = (lane>>4)*4 + reg
__global__ __launch_bounds__(256) void k_node(
    const float* __restrict__ x, const short* __restrict__ WaT,
    const float* __restrict__ ba, short* __restrict__ h_out,
    short* __restrict__ xbf_out) {
  __shared__ float xs[16][132];    // x tile (2-way bank conflicts = free)
  __shared__ float al_s[16][132];  // alpha tile
  int r0 = blockIdx.x * 16;
  int t = threadIdx.x;
  int w = t >> 6, l = t & 63;
  int g = l >> 4, c16 = l & 15;

  // coalesced stage: 16 rows x 128 f32 = 512 f32x4; 256 threads x 2
#pragma unroll
  for (int p = 0; p < 2; ++p) {
    int idx = t + p * 256;          // 0..511
    int row = idx >> 5, cv = idx & 31;
    f32x4 v = *(const f32x4*)(x + (size_t)(r0 + row) * D + cv * 4);
    *(f32x4*)&xs[row][cv * 4] = v;
  }
  __syncthreads();

  short8 a[4];
#pragma unroll
  for (int kt = 0; kt < 4; ++kt) {
    f32x4 v0 = *(const f32x4*)&xs[c16][kt * 32 + g * 8];
    f32x4 v1 = *(const f32x4*)&xs[c16][kt * 32 + g * 8 + 4];
    short8 tt;
    tt[0] = f2b(v0[0]); tt[1] = f2b(v0[1]); tt[2] = f2b(v0[2]); tt[3] = f2b(v0[3]);
    tt[4] = f2b(v1[0]); tt[5] = f2b(v1[1]); tt[6] = f2b(v1[2]); tt[7] = f2b(v1[3]);
    a[kt] = tt;
    *(short8*)(xbf_out + (size_t)(r0 + c16) * D + kt * 32 + g * 8) = tt;
  }

#pragma unroll
  for (int u = 0; u < 2; ++u) {
    int ct = w * 2 + u;
    int cc = ct * 16 + c16;
    f32x4 c = {0.f, 0.f, 0.f, 0.f};
#pragma unroll
    for (int kt = 0; kt < 4; ++kt) {
      short8 b = *(const short8*)(WaT + (size_t)cc * D + kt * 32 + g * 8);
      c = __builtin_amdgcn_mfma_f32_16x16x32_bf16(a[kt], b, c, 0, 0, 0);
    }
    float bav = ba[cc];
#pragma unroll
    for (int r = 0; r < 4; ++r) {
      float tv = c[r] + bav;
      al_s[g * 4 + r][cc] = 1.0f / (1.0f + __expf(-tv));
    }
  }
  __syncthreads();

  // wave w handles kt=w: h[row c16][w*32+g*8 ..] = x_f32 * alpha, bf16
  short8 hh;
#pragma unroll
  for (int q = 0; q < 8; ++q) {
    float av = al_s[c16][w * 32 + g * 8 + q];
    float xv = xs[c16][w * 32 + g * 8 + q];
    hh[q] = f2b(xv * av);
  }
  *(short8*)(h_out + (size_t)(r0 + c16) * D + w * 32 + g * 8) = hh;
}

// one pair-step: slots 4*T0+g and 4*T0+4+g for both nodes; 4 independent
// 16B gathers, register indices, branchless dummy-row clamp.
#define PSTEP(T0, C0A, C0B, C1A, C1B)                               \
  {                                                                 \
    int s0 = 4 * (T0) + g, s1 = s0 + 4;                             \
    int ra0 = s0 < deg0 ? (C0A) : NN;                               \
    int ra1 = s1 < deg0 ? (C0B) : NN;                               \
    int rb0 = s0 < deg1 ? (C1A) : NN;                               \
    int rb1 = s1 < deg1 ? (C1B) : NN;                               \
    short8 va0 = *(const short8*)(h + (size_t)ra0 * D + i * 8);     \
    short8 va1 = *(const short8*)(h + (size_t)ra1 * D + i * 8);     \
    short8 vb0 = *(const short8*)(h + (size_t)rb0 * D + i * 8);     \
    short8 vb1 = *(const short8*)(h + (size_t)rb1 * D + i * 8);     \
    _Pragma("unroll") for (int q = 0; q < 8; ++q) {                 \
      a0[q] += b2f(va0[q]) + b2f(va1[q]);                           \
      a1[q] += b2f(vb0[q]) + b2f(vb1[q]);                           \
    }                                                               \
  }

// ---------------- K3: fused aggregate + output GEMM (512 thr, 8 waves) ----
// Block = 16 nodes. Phase A: wave w -> node pair (base+2w, +1); indices
// hoisted to registers via shfl batches; unrolled wave-uniform bodies.
// Phase B: wave w computes output cols [16w, 16w+16); xbf tile LDS-staged.
__global__ __launch_bounds__(512) void k_fused(
    const int* __restrict__ cnt, const unsigned short* __restrict__ bucket,
    const short* __restrict__ h, const short* __restrict__ xbf,
    const short* __restrict__ WnT, const short* __restrict__ WgThi,
    const short* __restrict__ WgTlo, const float* __restrict__ bn,
    const float* __restrict__ bg, float* __restrict__ out) {
  __shared__ float st[16][132];
  __shared__ short xsb[16][132];
  int w = threadIdx.x >> 6, l = threadIdx.x & 63;
  int g = l >> 4, i = l & 15;
  int base = blockIdx.x * 16;

  // coalesced stage of xbf tile: 16 rows x 128 bf16 = 4KB; waves 0-3
  if (threadIdx.x < 256) {
    int idx = threadIdx.x;  // row = idx>>4, chunk = idx&15
    int row = idx >> 4, ch = idx & 15;
    *(short8*)&xsb[row][ch * 8] =
        *(const short8*)(xbf + (size_t)(base + row) * D + ch * 8);
  }

  // ---- Phase A ----
  {
    int n0 = base + 2 * w, n1 = n0 + 1;
    int deg0 = cnt[n0]; deg0 = deg0 < CAP ? deg0 : CAP;
    int deg1 = cnt[n1]; deg1 = deg1 < CAP ? deg1 : CAP;
    int dmax = deg0 > deg1 ? deg0 : deg1;
    int bc0 = bucket[(size_t)n0 * CAP + l];
    int bc1 = bucket[(size_t)n1 * CAP + l];
    float a0[8], a1[8];
#pragma unroll
    for (int q = 0; q < 8; ++q) { a0[q] = 0.f; a1[q] = 0.f; }

    // slots < 16: shfls hoisted
    int c00 = __shfl(bc0, g), c01 = __shfl(bc0, 4 + g);
    int c02 = __shfl(bc0, 8 + g), c03 = __shfl(bc0, 12 + g);
    int c10 = __shfl(bc1, g), c11 = __shfl(bc1, 4 + g);
    int c12 = __shfl(bc1, 8 + g), c13 = __shfl(bc1, 12 + g);
    PSTEP(0, c00, c01, c10, c11);
    if (dmax > 8) PSTEP(2, c02, c03, c12, c13);
    if (dmax > 16) {
      int c04 = __shfl(bc0, 16 + g), c05 = __shfl(bc0, 20 + g);
      int c14 = __shfl(bc1, 16 + g), c15 = __shfl(bc1, 20 + g);
      PSTEP(4, c04, c05, c14, c15);
    }
    if (dmax > 24) {
      int c06 = __shfl(bc0, 24 + g), c07 = __shfl(bc0, 28 + g);
      int c16_ = __shfl(bc1, 24 + g), c17 = __shfl(bc1, 28 + g);
      PSTEP(6, c06, c07, c16_, c17);
    }
    if (dmax > 32) {  // rare: P(deg>32 | Poisson(16)) ~ 1e-4
      for (int j = 32; j < dmax; j += 8) {
        int s0 = j + g, s1 = j + 4 + g;
        int d00 = __shfl(bc0, s0 & 63), d01 = __shfl(bc0, s1 & 63);
        int d10 = __shfl(bc1, s0 & 63), d11 = __shfl(bc1, s1 & 63);
        int ra0 = s0 < deg0 ? d00 : NN;
        int ra1 = s1 < deg0 ? d01 : NN;
        int rb0 = s0 < deg1 ? d10 : NN;
        int rb1 = s1 < deg1 ? d11 : NN;
        short8 va0 = *(const short8*)(h + (size_t)ra0 * D + i * 8);
        short8 va1 = *(const short8*)(h + (size_t)ra1 * D + i * 8);
        short8 vb0 = *(const short8*)(h + (size_t)rb0 * D + i * 8);
        short8 vb1 = *(const short8*)(h + (size_t)rb1 * D + i * 8);
#pragma unroll
        for (int q = 0; q < 8; ++q) {
          a0[q] += b2f(va0[q]) + b2f(va1[q]);
          a1[q] += b2f(vb0[q]) + b2f(vb1[q]);
        }
      }
    }
#pragma unroll
    for (int q = 0; q < 8; ++q) {
      a0[q] += __shfl_xor(a0[q], 16);
      a0[q] += __shfl_xor(a0[q], 32);
      a1[q] += __shfl_xor(a1[q], 16);
      a1[q] += __shfl_xor(a1[q], 32);
    }
    if (g == 0) {
      f32x4 lo = {a0[0], a0[1], a0[2], a0[3]};
      f32x4 hi = {a0[4], a0[5], a0[6], a0[7]};
      *(f32x4*)&st[w * 2][i * 8] = lo;
      *(f32x4*)&st[w * 2][i * 8 + 4] = hi;
    } else if (g == 1) {
      f32x4 lo = {a1[0], a1[1], a1[2], a1[3]};
      f32x4 hi = {a1[4], a1[5], a1[6], a1[7]};
      *(f32x4*)&st[w * 2 + 1][i * 8] = lo;
      *(f32x4*)&st[w * 2 + 1][i * 8 + 4] = hi;
    }
  }
  __syncthreads();

  // ---- Phase B: wave w computes cols [w*16, w*16+16) ----
  int cc = w * 16 + i;
  f32x4 c = {0.f, 0.f, 0.f, 0.f};
  float bias = bn[cc] + bg[cc];
#pragma unroll
  for (int kt = 0; kt < 4; ++kt) {
    short8 axf = *(const short8*)&xsb[i][kt * 32 + g * 8];
    const float* p = &st[i][kt * 32 + g * 8];
    f32x4 v0 = *(const f32x4*)p;
    f32x4 v1 = *(const f32x4*)(p + 4);
    short8 sh, sl;
#pragma unroll
    for (int jq = 0; jq < 4; ++jq) {
      short hh = f2b(v0[jq]);
      sh[jq] = hh;
      sl[jq] = f2b(v0[jq] - b2f(hh));
    }
#pragma unroll
    for (int jq = 0; jq < 4; ++jq) {
      short hh = f2b(v1[jq]);
      sh[4 + jq] = hh;
      sl[4 + jq] = f2b(v1[jq] - b2f(hh));
    }
    short8 bwn = *(const short8*)(WnT + (size_t)cc * D + kt * 32 + g * 8);
    short8 bh = *(const short8*)(WgThi + (size_t)cc * D + kt * 32 + g * 8);
    short8 bl = *(const short8*)(WgTlo + (size_t)cc * D + kt * 32 + g * 8);
    c = __builtin_amdgcn_mfma_f32_16x16x32_bf16(axf, bwn, c, 0, 0, 0);
    c = __builtin_amdgcn_mfma_f32_16x16x32_bf16(sh, bh, c, 0, 0, 0);
    c = __builtin_amdgcn_mfma_f32_16x16x32_bf16(sl, bh, c, 0, 0, 0);
    c = __builtin_amdgcn_mfma_f32_16x16x32_bf16(sh, bl, c, 0, 0, 0);
  }
#pragma unroll
  for (int r = 0; r < 4; ++r) {
    int rr = base + g * 4 + r;
    out[(size_t)rr * D + cc] = tanhf(c[r] + bias);
  }
}

extern "C" void kernel_launch(void* const* d_in, const int* in_sizes, int n_in,
                              void* d_out, int out_size, void* d_ws,
                              size_t ws_size, hipStream_t stream) {
  const float* x = (const float*)d_in[0];
  const int* ei = (const int*)d_in[1];
  const float* Wn_w = (const float*)d_in[2];
  const float* Wn_b = (const float*)d_in[3];
  const float* Wg_w = (const float*)d_in[4];
  const float* Wg_b = (const float*)d_in[5];
  const float* Wa_w = (const float*)d_in[6];
  const float* Wa_b = (const float*)d_in[7];

  char* ws = (char*)d_ws;
  short* WaT = (short*)(ws + 0);
  short* WnT = (short*)(ws + 32 * 1024);
  short* WgThi = (short*)(ws + 64 * 1024);
  short* WgTlo = (short*)(ws + 96 * 1024);
  int* cnt = (int*)(ws + 128 * 1024);  // 160 KB
  size_t off = 512 * 1024;
  short* h = (short*)(ws + off);  // (NN+1)*D*2 = 10.24 MB (+dummy row)
  off += (size_t)(NN + 1) * D * 2;
  short* xbf = (short*)(ws + off);  // 10.24 MB
  off += (size_t)NN * D * 2;
  unsigned short* bucket = (unsigned short*)(ws + off);  // 5.12 MB
  float* out = (float*)d_out;

  k_prep<<<64, 256, 0, stream>>>(Wn_w, Wg_w, Wa_w, WnT, WgThi, WgTlo, WaT,
                                 cnt, h);
  k_fill<<<(NE + 255) / 256, 256, 0, stream>>>(ei, cnt, bucket);
  k_node<<<NN / 16, 256, 0, stream>>>(x, WaT, Wa_b, h, xbf);
  k_fused<<<2500, 512, 0, stream>>>(cnt, bucket, h, xbf, WnT, WgThi, WgTlo,
                                    Wn_b, Wg_b, out);
}